// Round 2
// 1269.122 us; speedup vs baseline: 1.0911x; 1.0911x over previous
//
#include <hip/hip_runtime.h>

// AF-LSTM on MI355X. Sizes fixed: V=32000, D=H=512, B=64, T=256, A=4, 4H=2048.
// All float tensors f32; x,s int32; d_out f32 [64,512].
// R8 (passed, 1385us): sentinel-based direct data polling; persistent_lstm
// 757us (2.96us/step), MfmaUtil 1.8%, VALUBusy 4.8% -> pure latency chain.
// R9 (FAILED, abort): bundled fast-transcendentals + 4-chain MFMA + u64 poll
// remap. The u64 poll touched the exchange protocol and is the prime suspect.
// R10: keep the two safe VALU-only changes, revert poll to R8's exact 8x dword
// code. (a) gate math: ocml tanhf/expf+div (~350-400 instrs on the serial
// path) -> v_exp_f32/v_rcp_f32 fast sigmoid/tanh (~50 instrs). (b) 16-deep
// dependent MFMA accumulate chain -> 4 independent chains of 4.
// Exchange protocol (UNCHANGED from R8): publishers store h straight into Hs
// (relaxed agent, write-through); Hs pre-memset to 0xFFFFFFFF (bf16 NaN pair,
// unreachable for sigmoid*tanh outputs, also with fast ops); consumers
// relaxed-poll the exact dwords they need. No fences, no flags, no lockstep.

typedef __bf16 bf16x8 __attribute__((ext_vector_type(8)));
typedef float f32x4 __attribute__((ext_vector_type(4)));

#define B_ 64
#define T_ 256
#define D_ 512
#define H4 2048

__device__ __forceinline__ unsigned short f2bf(float f) {
    unsigned u = __float_as_uint(f);
    u += 0x7fffu + ((u >> 16) & 1u);   // round-to-nearest-even
    return (unsigned short)(u >> 16);
}
__device__ __forceinline__ float bf2f(unsigned short x) {
    return __uint_as_float(((unsigned)x) << 16);
}
__device__ __forceinline__ float bf2f_lo(unsigned u) { return __uint_as_float(u << 16); }
__device__ __forceinline__ float bf2f_hi(unsigned u) { return __uint_as_float(u & 0xffff0000u); }

// fast transcendentals: v_exp_f32 and v_rcp_f32 (~1-2 ulp). h goes through
// bf16 (0.4% rel) every step anyway, so this is noise. Outputs stay in
// [0,1]/[-1,1] for all finite inputs (exp overflow -> inf -> rcp -> 0), so
// the 0xFFFF sentinel remains unreachable.
__device__ __forceinline__ float frcp(float x) { return __builtin_amdgcn_rcpf(x); }
__device__ __forceinline__ float fast_sigmoid(float x) {
    return frcp(1.f + __expf(-x));
}
__device__ __forceinline__ float fast_tanh(float x) {
    // tanh(x) = 1 - 2/(exp(2x)+1); saturates correctly at +/-inf
    return 1.f - 2.f * frcp(1.f + __expf(2.f * x));
}

// ---------------------------------------------------------------------------
// C = A @ B^T GEMM, bf16 MFMA 16x16x32, 64x64 block tile, 4 waves.
// ---------------------------------------------------------------------------
__global__ __launch_bounds__(256)
void gemm_bt(const void* __restrict__ Abase, int a_f32,
             const int* __restrict__ gather_idx,
             const float* __restrict__ Bmat,
             const float* __restrict__ circ_src,
             const float* __restrict__ bias,
             unsigned short* __restrict__ outb,
             float* __restrict__ outf,
             int N, int K,
             long A_bstride, long out_bstride,
             int act)
{
    __shared__ __align__(16) unsigned short Asm[64 * 40];
    __shared__ __align__(16) unsigned short Bsm[64 * 40];

    const int bz = blockIdx.z;
    const int tile_n = blockIdx.x * 64;
    const int tile_m = blockIdx.y * 64;
    const int tid = threadIdx.x;
    const int lane = tid & 63;
    const int w = tid >> 6;
    const int wm = (w >> 1) * 32;
    const int wn = (w & 1) * 32;

    const int srow = tid >> 2;
    const int skc = (tid & 3) * 8;

    const float* arow_f = nullptr;
    const unsigned short* arow_h = nullptr;
    if (a_f32) {
        const float* Af = (const float*)Abase;
        if (gather_idx) arow_f = Af + (long)gather_idx[tile_m + srow] * K;
        else            arow_f = Af + (long)bz * A_bstride + (long)(tile_m + srow) * K;
    } else {
        arow_h = (const unsigned short*)Abase + (long)bz * A_bstride + (long)(tile_m + srow) * K;
    }
    const float* brow = nullptr;
    const float* csrc = nullptr;
    if (circ_src) csrc = circ_src + bz * 512;
    else brow = Bmat + (long)(tile_n + srow) * K;

    f32x4 zero4 = {0.f, 0.f, 0.f, 0.f};
    f32x4 acc00 = zero4, acc01 = zero4, acc10 = zero4, acc11 = zero4;

    const int fr = lane & 15;
    const int fq = (lane >> 4) * 8;

    for (int kc = 0; kc < K; kc += 32) {
        __syncthreads();
        if (a_f32) {
            float4 u0 = *(const float4*)(arow_f + kc + skc);
            float4 u1 = *(const float4*)(arow_f + kc + skc + 4);
            unsigned short tmp[8] __attribute__((aligned(16)));
            tmp[0] = f2bf(u0.x); tmp[1] = f2bf(u0.y); tmp[2] = f2bf(u0.z); tmp[3] = f2bf(u0.w);
            tmp[4] = f2bf(u1.x); tmp[5] = f2bf(u1.y); tmp[6] = f2bf(u1.z); tmp[7] = f2bf(u1.w);
            *(uint4*)&Asm[srow * 40 + skc] = *(const uint4*)tmp;
        } else {
            *(uint4*)&Asm[srow * 40 + skc] = *(const uint4*)(arow_h + kc + skc);
        }
        if (csrc) {
            unsigned short tmp[8] __attribute__((aligned(16)));
            int n_abs = tile_n + srow;
            #pragma unroll
            for (int j = 0; j < 8; j++) {
                int k_abs = kc + skc + j;
                tmp[j] = f2bf(csrc[(k_abs - n_abs) & 511]);
            }
            *(uint4*)&Bsm[srow * 40 + skc] = *(const uint4*)tmp;
        } else {
            float4 u0 = *(const float4*)(brow + kc + skc);
            float4 u1 = *(const float4*)(brow + kc + skc + 4);
            unsigned short tmp[8] __attribute__((aligned(16)));
            tmp[0] = f2bf(u0.x); tmp[1] = f2bf(u0.y); tmp[2] = f2bf(u0.z); tmp[3] = f2bf(u0.w);
            tmp[4] = f2bf(u1.x); tmp[5] = f2bf(u1.y); tmp[6] = f2bf(u1.z); tmp[7] = f2bf(u1.w);
            *(uint4*)&Bsm[srow * 40 + skc] = *(const uint4*)tmp;
        }
        __syncthreads();
        bf16x8 a0 = *(const bf16x8*)&Asm[(wm + fr) * 40 + fq];
        bf16x8 a1 = *(const bf16x8*)&Asm[(wm + 16 + fr) * 40 + fq];
        bf16x8 b0 = *(const bf16x8*)&Bsm[(wn + fr) * 40 + fq];
        bf16x8 b1 = *(const bf16x8*)&Bsm[(wn + 16 + fr) * 40 + fq];
        acc00 = __builtin_amdgcn_mfma_f32_16x16x32_bf16(a0, b0, acc00, 0, 0, 0);
        acc01 = __builtin_amdgcn_mfma_f32_16x16x32_bf16(a0, b1, acc01, 0, 0, 0);
        acc10 = __builtin_amdgcn_mfma_f32_16x16x32_bf16(a1, b0, acc10, 0, 0, 0);
        acc11 = __builtin_amdgcn_mfma_f32_16x16x32_bf16(a1, b1, acc11, 0, 0, 0);
    }

    #pragma unroll
    for (int mi = 0; mi < 2; mi++) {
        #pragma unroll
        for (int ni = 0; ni < 2; ni++) {
            f32x4 acc = (mi == 0) ? (ni == 0 ? acc00 : acc01)
                                  : (ni == 0 ? acc10 : acc11);
            #pragma unroll
            for (int rg = 0; rg < 4; rg++) {
                int row = tile_m + wm + mi * 16 + (lane >> 4) * 4 + rg;
                int col = tile_n + wn + ni * 16 + (lane & 15);
                float v = acc[rg];
                if (bias) v += bias[col];
                if (act == 1) v = fast_tanh(v);
                long oidx = (long)bz * out_bstride + (long)row * N + col;
                if (outb) outb[oidx] = f2bf(v);
                else outf[oidx] = v;
            }
        }
    }
}

// ---------------------------------------------------------------------------
// Persistent LSTM recurrence, 64 blocks x 512 threads (8 waves).
// bg = blockIdx>>4 owns batches [bg*16,+16); nb = blockIdx&15 owns cols
// [nb*32,+32) of every gate (128 W_hh rows in registers: 16 bf16x8/lane).
// Sync (R8-exact): NO flags, NO fences. h_t stored directly into Hs (relaxed
// agent, write-through). Hs pre-filled with 0xFFFFFFFF (bf16 NaN pair -- h
// can never produce it). Consumers poll exactly the 4096 dwords of
// Hs[:, t-1, :] they need until non-sentinel, reloading only pending ones.
// ---------------------------------------------------------------------------
#define WSTRIDE 520
#define SENT 0xFFFFFFFFu
#define ZL(g,r,d) zl[((g)*16+(r))*33+(d)]

__global__ __launch_bounds__(512)
void persistent_lstm(const float* __restrict__ Whh,         // f32 [2048][512]
                     const unsigned short* __restrict__ Zx, // bf16 [16384][2048]
                     unsigned int* __restrict__ Hsu)        // Hs as dwords [64*256*256]
{
    __shared__ __align__(16) unsigned short hsm[16 * WSTRIDE];  // 16,640 B
    __shared__ float zl[4 * 16 * 33];                           //  8,448 B

    const int bg = blockIdx.x >> 4;
    const int nb = blockIdx.x & 15;
    const int tid = threadIdx.x;
    const int w = tid >> 6;        // 0..7
    const int lane = tid & 63;
    const int fr = lane & 15;
    const int fq = (lane >> 4) * 8;
    const int g = w >> 1;          // gate
    const int f = w & 1;           // 16-row fragment within gate's 32 cols

    // ---- one-time: this wave's W_hh fragment rows into registers ----
    bf16x8 wfrag[16];
    {
        const float* wrow = Whh + (long)(g * 512 + nb * 32 + f * 16 + fr) * 512;
        #pragma unroll
        for (int c = 0; c < 16; c++) {
            int k0 = c * 32 + fq;
            float4 u0 = *(const float4*)(wrow + k0);
            float4 u1 = *(const float4*)(wrow + k0 + 4);
            unsigned short tmp[8] __attribute__((aligned(16)));
            tmp[0] = f2bf(u0.x); tmp[1] = f2bf(u0.y); tmp[2] = f2bf(u0.z); tmp[3] = f2bf(u0.w);
            tmp[4] = f2bf(u1.x); tmp[5] = f2bf(u1.y); tmp[6] = f2bf(u1.z); tmp[7] = f2bf(u1.w);
            wfrag[c] = *(const bf16x8*)tmp;
        }
    }

    // staging ownership (R8-exact): thread handles 8 dwords; idx = it*512+tid,
    // r = idx>>8 (batch row 0..15), dpair = idx&255 (col pair 0..255)
    int st_r[8], st_dp[8];
    #pragma unroll
    for (int it = 0; it < 8; it++) {
        int idx = it * 512 + tid;
        st_r[it] = idx >> 8;
        st_dp[it] = idx & 255;
    }

    // gate-math ownership (threads 0..255): row grow, col pair (d0, d0+1)
    const int grow = (tid & 255) >> 4;
    const int d0 = (tid & 15) * 2;
    const int b_own = bg * 16 + grow;
    const int dg = nb * 32 + d0;
    float ca = 0.f, cb = 0.f;      // cell state in registers (threads < 256)

    f32x4 zero4 = {0.f, 0.f, 0.f, 0.f};

    for (int t = 0; t < T_; t++) {
        // Zx gate pre-activations: independent of h -> issue early
        unsigned zi_u = 0, zf_u = 0, zg_u = 0, zo_u = 0;
        if (tid < 256) {
            const long zb = ((long)b_own * T_ + t) * H4 + dg;
            zi_u = *(const unsigned*)&Zx[zb + 0 * 512];
            zf_u = *(const unsigned*)&Zx[zb + 1 * 512];
            zg_u = *(const unsigned*)&Zx[zb + 2 * 512];
            zo_u = *(const unsigned*)&Zx[zb + 3 * 512];
        }

        f32x4 acc = zero4;
        if (t > 0) {
            // poll-stage h_{t-1}: 4096 dwords of Hs[bg*16..+16][t-1][*]
            unsigned vv[8];
            long ad[8];
            #pragma unroll
            for (int it = 0; it < 8; it++) {
                ad[it] = ((long)(bg * 16 + st_r[it]) * T_ + (t - 1)) * 256 + st_dp[it];
                vv[it] = __hip_atomic_load(Hsu + ad[it], __ATOMIC_RELAXED,
                                           __HIP_MEMORY_SCOPE_AGENT);
            }
            while (true) {
                bool pend = false;
                #pragma unroll
                for (int it = 0; it < 8; it++) {
                    if (vv[it] == SENT) {
                        vv[it] = __hip_atomic_load(Hsu + ad[it], __ATOMIC_RELAXED,
                                                   __HIP_MEMORY_SCOPE_AGENT);
                        pend = true;
                    }
                }
                if (!__ballot(pend)) break;
                __builtin_amdgcn_s_sleep(1);
            }
            #pragma unroll
            for (int it = 0; it < 8; it++) {
                *(unsigned*)&hsm[st_r[it] * WSTRIDE + st_dp[it] * 2] = vv[it];
            }
            __syncthreads();   // S1: hsm staged (also fences prev-iter zl reads)
            // z_frag = h_{t-1}[16x512] @ Wfrag^T : 16 MFMAs over K=512,
            // 4 independent accumulator chains (dep-latency 4 deep, not 16)
            const unsigned short* arow = hsm + fr * WSTRIDE;
            f32x4 ac0 = zero4, ac1 = zero4, ac2 = zero4, ac3 = zero4;
            #pragma unroll
            for (int c = 0; c < 16; c += 4) {
                bf16x8 x0 = *(const bf16x8*)(arow + (c + 0) * 32 + fq);
                bf16x8 x1 = *(const bf16x8*)(arow + (c + 1) * 32 + fq);
                bf16x8 x2 = *(const bf16x8*)(arow + (c + 2) * 32 + fq);
                bf16x8 x3 = *(const bf16x8*)(arow + (c + 3) * 32 + fq);
                ac0 = __builtin_amdgcn_mfma_f32_16x16x32_bf16(x0, wfrag[c + 0], ac0, 0, 0, 0);
                ac1 = __builtin_amdgcn_mfma_f32_16x16x32_bf16(x1, wfrag[c + 1], ac1, 0, 0, 0);
                ac2 = __builtin_amdgcn_mfma_f32_16x16x32_bf16(x2, wfrag[c + 2], ac2, 0, 0, 0);
                ac3 = __builtin_amdgcn_mfma_f32_16x16x32_bf16(x3, wfrag[c + 3], ac3, 0, 0, 0);
            }
            acc = (ac0 + ac1) + (ac2 + ac3);
        }
        // scatter z to LDS (C/D: col=lane&15, row=(lane>>4)*4+reg)
        {
            const int q4 = (lane >> 4) * 4;
            const int cl = f * 16 + (lane & 15);
            #pragma unroll
            for (int rg = 0; rg < 4; rg++) {
                ZL(g, q4 + rg, cl) = acc[rg];
            }
        }
        __syncthreads();       // S2: zl complete (and hsm reads drained)
        // gate math on threads 0..255 (wave-uniform branch)
        if (tid < 256) {
            float zi0 = ZL(0, grow, d0)     + bf2f_lo(zi_u);
            float zi1 = ZL(0, grow, d0 + 1) + bf2f_hi(zi_u);
            float zf0 = ZL(1, grow, d0)     + bf2f_lo(zf_u);
            float zf1 = ZL(1, grow, d0 + 1) + bf2f_hi(zf_u);
            float zg0 = ZL(2, grow, d0)     + bf2f_lo(zg_u);
            float zg1 = ZL(2, grow, d0 + 1) + bf2f_hi(zg_u);
            float zo0 = ZL(3, grow, d0)     + bf2f_lo(zo_u);
            float zo1 = ZL(3, grow, d0 + 1) + bf2f_hi(zo_u);

            ca = fast_sigmoid(zf0) * ca + fast_sigmoid(zi0) * fast_tanh(zg0);
            cb = fast_sigmoid(zf1) * cb + fast_sigmoid(zi1) * fast_tanh(zg1);
            float h0 = fast_sigmoid(zo0) * fast_tanh(ca);
            float h1 = fast_sigmoid(zo1) * fast_tanh(cb);

            unsigned hp = (unsigned)f2bf(h0) | ((unsigned)f2bf(h1) << 16);
            // publish: history and exchange in one store (write-through)
            __hip_atomic_store(Hsu + ((long)b_own * T_ + t) * 256 + nb * 16 + (tid & 15),
                               hp, __ATOMIC_RELAXED, __HIP_MEMORY_SCOPE_AGENT);
        }
        // no trailing sync: S1 of the next iteration protects zl reuse
    }
}

// ---------------------------------------------------------------------------
// Aspect normalization (unchanged)
// ---------------------------------------------------------------------------
__global__ __launch_bounds__(64)
void aspect_norm(const int* __restrict__ s,
                 const float* __restrict__ embed,
                 float* __restrict__ s_norm)
{
    __shared__ int sidx[256];
    const int tid = threadIdx.x;
    const int d = blockIdx.x * 64 + tid;
    for (int i = tid; i < 256; i += 64) sidx[i] = s[i];
    __syncthreads();
    float sum = 0.f, sq = 0.f;
    for (int i = 0; i < 256; i++) {
        float v = embed[(long)sidx[i] * D_ + d];
        sum += v; sq += v * v;
    }
    float mu = sum * (1.f / 256.f);
    float var = sq * (1.f / 256.f) - mu * mu;
    float rstd = rsqrtf(var + 1e-5f);
    for (int b = 0; b < 64; b++) {
        float acc = 0.f;
        #pragma unroll
        for (int a = 0; a < 4; a++) {
            acc += embed[(long)sidx[b * 4 + a] * D_ + d] - mu;
        }
        s_norm[b * D_ + d] = acc * rstd;
    }
}

// ---------------------------------------------------------------------------
// Softmax over T + r reduction. Fast exp (v_exp_f32): was ~512 expf/thread.
// ---------------------------------------------------------------------------
__global__ __launch_bounds__(256)
void attn_r(const float* __restrict__ apre,
            const unsigned short* __restrict__ Hs,
            float* __restrict__ r)
{
    const int b = blockIdx.y;
    const int d = blockIdx.x * 256 + threadIdx.x;
    const float* ap = apre + (long)b * T_ * D_ + d;
    const unsigned short* hp = Hs + (long)b * T_ * D_ + d;
    float mx = ap[0], sm = 1.f;
    for (int t = 1; t < T_; t++) {
        float v = ap[(long)t * D_];
        if (v > mx) { sm = sm * __expf(mx - v) + 1.f; mx = v; }
        else sm += __expf(v - mx);
    }
    float acc = 0.f;
    for (int t = 0; t < T_; t++) {
        acc += __expf(ap[(long)t * D_] - mx) * bf2f(hp[(long)t * D_]);
    }
    r[b * D_ + d] = acc / sm;
}

// ---------------------------------------------------------------------------
// h_star = tanh(r @ w_p^T + Hs[:, -1] @ w_x^T)
// ---------------------------------------------------------------------------
__global__ __launch_bounds__(256)
void hstar_kernel(const float* __restrict__ r,
                  const unsigned short* __restrict__ Hs,
                  const float* __restrict__ w_p,
                  const float* __restrict__ w_x,
                  float* __restrict__ h_star)
{
    __shared__ float rs[512];
    __shared__ float hts[512];
    const int b = blockIdx.x, tid = threadIdx.x;
    const long hlast = ((long)b * T_ + (T_ - 1)) * D_;
    rs[tid] = r[b * D_ + tid];
    rs[tid + 256] = r[b * D_ + 256 + tid];
    hts[tid] = bf2f(Hs[hlast + tid]);
    hts[tid + 256] = bf2f(Hs[hlast + 256 + tid]);
    __syncthreads();
    for (int d = tid; d < 512; d += 256) {
        const float* wp = w_p + (long)d * D_;
        const float* wx = w_x + (long)d * D_;
        float acc = 0.f;
        for (int e = 0; e < 512; e += 4) {
            float4 p1 = *(const float4*)(wp + e);
            float4 p2 = *(const float4*)(wx + e);
            acc += p1.x * rs[e] + p1.y * rs[e + 1] + p1.z * rs[e + 2] + p1.w * rs[e + 3];
            acc += p2.x * hts[e] + p2.y * hts[e + 1] + p2.z * hts[e + 2] + p2.w * hts[e + 3];
        }
        h_star[b * D_ + d] = fast_tanh(acc);
    }
}

// ---------------------------------------------------------------------------
// out = softmax(h_star @ w_f^T + b_f)
// ---------------------------------------------------------------------------
__global__ __launch_bounds__(256)
void out_kernel(const float* __restrict__ h_star,
                const float* __restrict__ w_f,
                const float* __restrict__ b_f,
                float* __restrict__ out)
{
    __shared__ float hs[512];
    __shared__ float lg[512];
    __shared__ float red[8];
    const int b = blockIdx.x, tid = threadIdx.x;
    hs[tid] = h_star[b * D_ + tid];
    hs[tid + 256] = h_star[b * D_ + 256 + tid];
    __syncthreads();
    for (int d = tid; d < 512; d += 256) {
        const float* wr = w_f + (long)d * D_;
        float acc = b_f[d];
        for (int e = 0; e < 512; e += 4) {
            float4 p = *(const float4*)(wr + e);
            acc += p.x * hs[e] + p.y * hs[e + 1] + p.z * hs[e + 2] + p.w * hs[e + 3];
        }
        lg[d] = acc;
    }
    __syncthreads();
    float m0 = fmaxf(lg[tid], lg[tid + 256]);
    for (int off = 32; off > 0; off >>= 1) m0 = fmaxf(m0, __shfl_down(m0, off, 64));
    if ((tid & 63) == 0) red[tid >> 6] = m0;
    __syncthreads();
    float bmax = fmaxf(fmaxf(red[0], red[1]), fmaxf(red[2], red[3]));
    float e0 = __expf(lg[tid] - bmax);
    float e1 = __expf(lg[tid + 256] - bmax);
    float s0 = e0 + e1;
    for (int off = 32; off > 0; off >>= 1) s0 += __shfl_down(s0, off, 64);
    if ((tid & 63) == 0) red[4 + (tid >> 6)] = s0;
    __syncthreads();
    float inv = 1.f / (red[4] + red[5] + red[6] + red[7]);
    out[b * D_ + tid] = e0 * inv;
    out[b * D_ + 256 + tid] = e1 * inv;
}

// ---------------------------------------------------------------------------
extern "C" void kernel_launch(void* const* d_in, const int* in_sizes, int n_in,
                              void* d_out, int out_size, void* d_ws, size_t ws_size,
                              hipStream_t stream)
{
    (void)in_sizes; (void)n_in; (void)out_size; (void)ws_size;

    const int* x = (const int*)d_in[0];
    const int* s = (const int*)d_in[1];
    const float* embed  = (const float*)d_in[2];
    const float* W_ih   = (const float*)d_in[3];
    const float* W_hh   = (const float*)d_in[4];
    const float* b_lstm = (const float*)d_in[5];
    const float* w_y = (const float*)d_in[6];
    const float* w_t = (const float*)d_in[7];
    const float* w_p = (const float*)d_in[8];
    const float* w_x = (const float*)d_in[9];
    const float* w_f = (const float*)d_in[10];
    const float* b_f = (const float*)d_in[11];

    // Workspace (overlaid), peak ~86.5 MB:
    //   [0,64MiB)   phase1: Zx bf16 [16384][2048]
    //               phase2: apre f32 @0, mbuf bf16 @32MiB, Ybuf bf16 @48MiB
    //   [64MiB,+16MiB) Hs bf16 (doubles as the h exchange; sentinel-filled)
    //   @86114304: s_norm, @86245376: rbuf, @86376448: hstar
    char* ws = (char*)d_ws;
    unsigned short* Zx   = (unsigned short*)(ws + 0);
    float*          apre = (float*)(ws + 0);
    unsigned short* mbuf = (unsigned short*)(ws + 33554432);
    unsigned short* Ybuf = (unsigned short*)(ws + 50331648);
    unsigned short* Hs   = (unsigned short*)(ws + 67108864);
    float* s_norm = (float*)(ws + 86114304);
    float* rbuf   = (float*)(ws + 86245376);
    float* hstar  = (float*)(ws + 86376448);

    // 0) sentinel-fill Hs (0xFF bytes -> 0xFFFFFFFF dwords = bf16 NaN pairs)
    hipMemsetAsync(Hs, 0xFF, (size_t)B_ * T_ * D_ * 2, stream);

    // 1) aspect normalization
    aspect_norm<<<dim3(8), dim3(64), 0, stream>>>(s, embed, s_norm);

    // 2) G1: Zx = embed[x] @ W_ih^T + b_lstm  (M=16384, N=2048, K=512)
    gemm_bt<<<dim3(32, 256, 1), dim3(256), 0, stream>>>(
        embed, 1, x, W_ih, nullptr, b_lstm, Zx, nullptr,
        2048, 512, 0L, 0L, 0);

    // 3) recurrence: ONE persistent kernel, 64 blocks x 512 threads
    persistent_lstm<<<dim3(64), dim3(512), 0, stream>>>(
        W_hh, Zx, (unsigned int*)Hs);

    // ---- phase 2: Zx dead; region reused for apre/mbuf/Ybuf ----

    // 4) G2: m[b] = Hs[b] @ circ(s_norm[b])^T
    gemm_bt<<<dim3(8, 4, 64), dim3(256), 0, stream>>>(
        Hs, 0, nullptr, nullptr, s_norm, nullptr, mbuf, nullptr,
        512, 512, (long)(T_ * D_), (long)(T_ * D_), 0);

    // 5) G3: Y = tanh(m @ w_y^T)
    gemm_bt<<<dim3(8, 256, 1), dim3(256), 0, stream>>>(
        mbuf, 0, nullptr, w_y, nullptr, nullptr, Ybuf, nullptr,
        512, 512, 0L, 0L, 1);

    // 6) G4: apre = Y @ w_t^T
    gemm_bt<<<dim3(8, 256, 1), dim3(256), 0, stream>>>(
        Ybuf, 0, nullptr, w_t, nullptr, nullptr, nullptr, apre,
        512, 512, 0L, 0L, 0);

    // 7) softmax over T + r reduction
    attn_r<<<dim3(2, 64), dim3(256), 0, stream>>>(apre, Hs, rbuf);

    // 8) h_star
    hstar_kernel<<<dim3(64), dim3(256), 0, stream>>>(rbuf, Hs, w_p, w_x, hstar);

    // 9) final logits + softmax
    out_kernel<<<dim3(64), dim3(256), 0, stream>>>(hstar, w_f, b_f, (float*)d_out);
}

// Round 3
// 1094.698 us; speedup vs baseline: 1.2649x; 1.1593x over previous
//
#include <hip/hip_runtime.h>

// AF-LSTM on MI355X. Sizes fixed: V=32000, D=H=512, B=64, T=256, A=4, 4H=2048.
// All float tensors f32; x,s int32; d_out f32 [64,512].
// R10 (passed, 1269us): fast transcendentals + 4-chain MFMA; persistent_lstm
// 661us (2.58us/step ~= 6200cy). Counters: MfmaUtil 2.05, VALUBusy 3.36 ->
// still latency-chain. Decomposition: detection ~2 rounds (~2500cy) because
// the poll checked values loaded in the PREVIOUS round (+s_sleep).
// R11: (a) poll loop restructured check-fresh-in-same-round: issue all 8
// reloads grouped (branchless reload-all; data is write-once so harmless),
// then check the just-loaded values -> detection <= 1 load latency after
// visibility. Addresses/widths/ordering semantics byte-identical to R10's
// proven protocol. (b) gemm_bt 64x64 tile -> 128x128 tile (4 waves, each
// 64x64 = 4x4 16x16x32 frags): 2x MFMA:staging ratio (m93 ladder step);
// feeds G1 (M=16384,N=2048,K=512), G2 (batched), G3/G4 (M=16384,N=512).
// Exchange protocol (UNCHANGED): publishers store h straight into Hs
// (relaxed agent, write-through); Hs pre-memset to 0xFFFFFFFF (bf16 NaN
// pair, unreachable for sigmoid*tanh outputs); consumers relaxed-poll the
// exact dwords they need. No fences, no flags, no lockstep.

typedef __bf16 bf16x8 __attribute__((ext_vector_type(8)));
typedef float f32x4 __attribute__((ext_vector_type(4)));

#define B_ 64
#define T_ 256
#define D_ 512
#define H4 2048

__device__ __forceinline__ unsigned short f2bf(float f) {
    unsigned u = __float_as_uint(f);
    u += 0x7fffu + ((u >> 16) & 1u);   // round-to-nearest-even
    return (unsigned short)(u >> 16);
}
__device__ __forceinline__ float bf2f(unsigned short x) {
    return __uint_as_float(((unsigned)x) << 16);
}
__device__ __forceinline__ float bf2f_lo(unsigned u) { return __uint_as_float(u << 16); }
__device__ __forceinline__ float bf2f_hi(unsigned u) { return __uint_as_float(u & 0xffff0000u); }

// fast transcendentals: v_exp_f32 and v_rcp_f32 (~1-2 ulp). h goes through
// bf16 (0.4% rel) every step anyway, so this is noise. Outputs stay in
// [0,1]/[-1,1] for all finite inputs, so the 0xFFFF sentinel is unreachable.
__device__ __forceinline__ float frcp(float x) { return __builtin_amdgcn_rcpf(x); }
__device__ __forceinline__ float fast_sigmoid(float x) {
    return frcp(1.f + __expf(-x));
}
__device__ __forceinline__ float fast_tanh(float x) {
    // tanh(x) = 1 - 2/(exp(2x)+1); saturates correctly at +/-inf
    return 1.f - 2.f * frcp(1.f + __expf(2.f * x));
}

// ---------------------------------------------------------------------------
// C = A @ B^T GEMM, bf16 MFMA 16x16x32. R11: 128x128 block tile, 4 waves,
// each wave computes a 64x64 sub-tile as 4x4 fragments (16 MFMA / K-step).
// Staging: each of 256 threads stages 16 elts of A and 16 of B per K-step
// (two b128 LDS writes each). LDS row stride 40 ushorts (80B) keeps the
// fragment ds_read_b128 at 2-way bank aliasing (free).
// ---------------------------------------------------------------------------
__global__ __launch_bounds__(256)
void gemm_bt(const void* __restrict__ Abase, int a_f32,
             const int* __restrict__ gather_idx,
             const float* __restrict__ Bmat,
             const float* __restrict__ circ_src,
             const float* __restrict__ bias,
             unsigned short* __restrict__ outb,
             float* __restrict__ outf,
             int N, int K,
             long A_bstride, long out_bstride,
             int act)
{
    __shared__ __align__(16) unsigned short Asm[128 * 40];
    __shared__ __align__(16) unsigned short Bsm[128 * 40];

    const int bz = blockIdx.z;
    const int tile_n = blockIdx.x * 128;
    const int tile_m = blockIdx.y * 128;
    const int tid = threadIdx.x;
    const int lane = tid & 63;
    const int w = tid >> 6;
    const int wm = (w >> 1) * 64;
    const int wn = (w & 1) * 64;

    const int srow = tid >> 1;        // 0..127
    const int skc = (tid & 1) * 16;   // 0 or 16

    const float* arow_f = nullptr;
    const unsigned short* arow_h = nullptr;
    if (a_f32) {
        const float* Af = (const float*)Abase;
        if (gather_idx) arow_f = Af + (long)gather_idx[tile_m + srow] * K;
        else            arow_f = Af + (long)bz * A_bstride + (long)(tile_m + srow) * K;
    } else {
        arow_h = (const unsigned short*)Abase + (long)bz * A_bstride + (long)(tile_m + srow) * K;
    }
    const float* brow = nullptr;
    const float* csrc = nullptr;
    if (circ_src) csrc = circ_src + bz * 512;
    else brow = Bmat + (long)(tile_n + srow) * K;

    f32x4 zero4 = {0.f, 0.f, 0.f, 0.f};
    f32x4 acc[4][4];
    #pragma unroll
    for (int mi = 0; mi < 4; mi++)
        #pragma unroll
        for (int ni = 0; ni < 4; ni++) acc[mi][ni] = zero4;

    const int fr = lane & 15;
    const int fq = (lane >> 4) * 8;

    for (int kc = 0; kc < K; kc += 32) {
        __syncthreads();
        if (a_f32) {
            float4 u0 = *(const float4*)(arow_f + kc + skc);
            float4 u1 = *(const float4*)(arow_f + kc + skc + 4);
            float4 u2 = *(const float4*)(arow_f + kc + skc + 8);
            float4 u3 = *(const float4*)(arow_f + kc + skc + 12);
            unsigned short tmp[16] __attribute__((aligned(16)));
            tmp[0] = f2bf(u0.x); tmp[1] = f2bf(u0.y); tmp[2]  = f2bf(u0.z); tmp[3]  = f2bf(u0.w);
            tmp[4] = f2bf(u1.x); tmp[5] = f2bf(u1.y); tmp[6]  = f2bf(u1.z); tmp[7]  = f2bf(u1.w);
            tmp[8] = f2bf(u2.x); tmp[9] = f2bf(u2.y); tmp[10] = f2bf(u2.z); tmp[11] = f2bf(u2.w);
            tmp[12] = f2bf(u3.x); tmp[13] = f2bf(u3.y); tmp[14] = f2bf(u3.z); tmp[15] = f2bf(u3.w);
            *(uint4*)&Asm[srow * 40 + skc]     = *(const uint4*)tmp;
            *(uint4*)&Asm[srow * 40 + skc + 8] = *(const uint4*)(tmp + 8);
        } else {
            *(uint4*)&Asm[srow * 40 + skc]     = *(const uint4*)(arow_h + kc + skc);
            *(uint4*)&Asm[srow * 40 + skc + 8] = *(const uint4*)(arow_h + kc + skc + 8);
        }
        if (csrc) {
            unsigned short tmp[16] __attribute__((aligned(16)));
            int n_abs = tile_n + srow;
            #pragma unroll
            for (int j = 0; j < 16; j++) {
                int k_abs = kc + skc + j;
                tmp[j] = f2bf(csrc[(k_abs - n_abs) & 511]);
            }
            *(uint4*)&Bsm[srow * 40 + skc]     = *(const uint4*)tmp;
            *(uint4*)&Bsm[srow * 40 + skc + 8] = *(const uint4*)(tmp + 8);
        } else {
            float4 u0 = *(const float4*)(brow + kc + skc);
            float4 u1 = *(const float4*)(brow + kc + skc + 4);
            float4 u2 = *(const float4*)(brow + kc + skc + 8);
            float4 u3 = *(const float4*)(brow + kc + skc + 12);
            unsigned short tmp[16] __attribute__((aligned(16)));
            tmp[0] = f2bf(u0.x); tmp[1] = f2bf(u0.y); tmp[2]  = f2bf(u0.z); tmp[3]  = f2bf(u0.w);
            tmp[4] = f2bf(u1.x); tmp[5] = f2bf(u1.y); tmp[6]  = f2bf(u1.z); tmp[7]  = f2bf(u1.w);
            tmp[8] = f2bf(u2.x); tmp[9] = f2bf(u2.y); tmp[10] = f2bf(u2.z); tmp[11] = f2bf(u2.w);
            tmp[12] = f2bf(u3.x); tmp[13] = f2bf(u3.y); tmp[14] = f2bf(u3.z); tmp[15] = f2bf(u3.w);
            *(uint4*)&Bsm[srow * 40 + skc]     = *(const uint4*)tmp;
            *(uint4*)&Bsm[srow * 40 + skc + 8] = *(const uint4*)(tmp + 8);
        }
        __syncthreads();
        bf16x8 av[4], bv[4];
        #pragma unroll
        for (int mi = 0; mi < 4; mi++)
            av[mi] = *(const bf16x8*)&Asm[(wm + mi * 16 + fr) * 40 + fq];
        #pragma unroll
        for (int ni = 0; ni < 4; ni++)
            bv[ni] = *(const bf16x8*)&Bsm[(wn + ni * 16 + fr) * 40 + fq];
        #pragma unroll
        for (int mi = 0; mi < 4; mi++)
            #pragma unroll
            for (int ni = 0; ni < 4; ni++)
                acc[mi][ni] = __builtin_amdgcn_mfma_f32_16x16x32_bf16(
                    av[mi], bv[ni], acc[mi][ni], 0, 0, 0);
    }

    #pragma unroll
    for (int mi = 0; mi < 4; mi++) {
        #pragma unroll
        for (int ni = 0; ni < 4; ni++) {
            #pragma unroll
            for (int rg = 0; rg < 4; rg++) {
                int row = tile_m + wm + mi * 16 + (lane >> 4) * 4 + rg;
                int col = tile_n + wn + ni * 16 + (lane & 15);
                float v = acc[mi][ni][rg];
                if (bias) v += bias[col];
                if (act == 1) v = fast_tanh(v);
                long oidx = (long)bz * out_bstride + (long)row * N + col;
                if (outb) outb[oidx] = f2bf(v);
                else outf[oidx] = v;
            }
        }
    }
}

// ---------------------------------------------------------------------------
// Persistent LSTM recurrence, 64 blocks x 512 threads (8 waves).
// bg = blockIdx>>4 owns batches [bg*16,+16); nb = blockIdx&15 owns cols
// [nb*32,+32) of every gate (128 W_hh rows in registers: 16 bf16x8/lane).
// Sync: NO flags, NO fences. h_t stored directly into Hs (relaxed agent,
// write-through). Hs pre-filled with 0xFFFFFFFF (bf16 NaN pair -- h can
// never produce it). Consumers poll exactly the 4096 dwords of Hs[:, t-1, :]
// they need. R11 poll: check initial values; while any SENT, reload ALL 8
// (grouped, branchless -- data is write-once so re-reading fresh dwords is
// harmless) and re-check the FRESH values in the same round.
// ---------------------------------------------------------------------------
#define WSTRIDE 520
#define SENT 0xFFFFFFFFu
#define ZL(g,r,d) zl[((g)*16+(r))*33+(d)]

__global__ __launch_bounds__(512)
void persistent_lstm(const float* __restrict__ Whh,         // f32 [2048][512]
                     const unsigned short* __restrict__ Zx, // bf16 [16384][2048]
                     unsigned int* __restrict__ Hsu)        // Hs as dwords [64*256*256]
{
    __shared__ __align__(16) unsigned short hsm[16 * WSTRIDE];  // 16,640 B
    __shared__ float zl[4 * 16 * 33];                           //  8,448 B

    const int bg = blockIdx.x >> 4;
    const int nb = blockIdx.x & 15;
    const int tid = threadIdx.x;
    const int w = tid >> 6;        // 0..7
    const int lane = tid & 63;
    const int fr = lane & 15;
    const int fq = (lane >> 4) * 8;
    const int g = w >> 1;          // gate
    const int f = w & 1;           // 16-row fragment within gate's 32 cols

    // ---- one-time: this wave's W_hh fragment rows into registers ----
    bf16x8 wfrag[16];
    {
        const float* wrow = Whh + (long)(g * 512 + nb * 32 + f * 16 + fr) * 512;
        #pragma unroll
        for (int c = 0; c < 16; c++) {
            int k0 = c * 32 + fq;
            float4 u0 = *(const float4*)(wrow + k0);
            float4 u1 = *(const float4*)(wrow + k0 + 4);
            unsigned short tmp[8] __attribute__((aligned(16)));
            tmp[0] = f2bf(u0.x); tmp[1] = f2bf(u0.y); tmp[2] = f2bf(u0.z); tmp[3] = f2bf(u0.w);
            tmp[4] = f2bf(u1.x); tmp[5] = f2bf(u1.y); tmp[6] = f2bf(u1.z); tmp[7] = f2bf(u1.w);
            wfrag[c] = *(const bf16x8*)tmp;
        }
    }

    // staging ownership (R8-exact): thread handles 8 dwords; idx = it*512+tid,
    // r = idx>>8 (batch row 0..15), dpair = idx&255 (col pair 0..255)
    int st_r[8], st_dp[8];
    #pragma unroll
    for (int it = 0; it < 8; it++) {
        int idx = it * 512 + tid;
        st_r[it] = idx >> 8;
        st_dp[it] = idx & 255;
    }

    // gate-math ownership (threads 0..255): row grow, col pair (d0, d0+1)
    const int grow = (tid & 255) >> 4;
    const int d0 = (tid & 15) * 2;
    const int b_own = bg * 16 + grow;
    const int dg = nb * 32 + d0;
    float ca = 0.f, cb = 0.f;      // cell state in registers (threads < 256)

    f32x4 zero4 = {0.f, 0.f, 0.f, 0.f};

    for (int t = 0; t < T_; t++) {
        // Zx gate pre-activations: independent of h -> issue early
        unsigned zi_u = 0, zf_u = 0, zg_u = 0, zo_u = 0;
        if (tid < 256) {
            const long zb = ((long)b_own * T_ + t) * H4 + dg;
            zi_u = *(const unsigned*)&Zx[zb + 0 * 512];
            zf_u = *(const unsigned*)&Zx[zb + 1 * 512];
            zg_u = *(const unsigned*)&Zx[zb + 2 * 512];
            zo_u = *(const unsigned*)&Zx[zb + 3 * 512];
        }

        f32x4 acc = zero4;
        if (t > 0) {
            // poll-stage h_{t-1}: 4096 dwords of Hs[bg*16..+16][t-1][*]
            unsigned vv[8];
            long ad[8];
            #pragma unroll
            for (int it = 0; it < 8; it++) {
                ad[it] = ((long)(bg * 16 + st_r[it]) * T_ + (t - 1)) * 256 + st_dp[it];
                vv[it] = __hip_atomic_load(Hsu + ad[it], __ATOMIC_RELAXED,
                                           __HIP_MEMORY_SCOPE_AGENT);
            }
            // check current values; if any pending, reload ALL (grouped) and
            // re-check the freshly loaded values in the same round.
            while (true) {
                bool pend = false;
                #pragma unroll
                for (int it = 0; it < 8; it++) pend |= (vv[it] == SENT);
                if (!__ballot(pend)) break;
                #pragma unroll
                for (int it = 0; it < 8; it++) {
                    vv[it] = __hip_atomic_load(Hsu + ad[it], __ATOMIC_RELAXED,
                                               __HIP_MEMORY_SCOPE_AGENT);
                }
            }
            #pragma unroll
            for (int it = 0; it < 8; it++) {
                *(unsigned*)&hsm[st_r[it] * WSTRIDE + st_dp[it] * 2] = vv[it];
            }
            __syncthreads();   // S1: hsm staged (also fences prev-iter zl reads)
            // z_frag = h_{t-1}[16x512] @ Wfrag^T : 16 MFMAs over K=512,
            // 4 independent accumulator chains (dep-latency 4 deep, not 16)
            const unsigned short* arow = hsm + fr * WSTRIDE;
            f32x4 ac0 = zero4, ac1 = zero4, ac2 = zero4, ac3 = zero4;
            #pragma unroll
            for (int c = 0; c < 16; c += 4) {
                bf16x8 x0 = *(const bf16x8*)(arow + (c + 0) * 32 + fq);
                bf16x8 x1 = *(const bf16x8*)(arow + (c + 1) * 32 + fq);
                bf16x8 x2 = *(const bf16x8*)(arow + (c + 2) * 32 + fq);
                bf16x8 x3 = *(const bf16x8*)(arow + (c + 3) * 32 + fq);
                ac0 = __builtin_amdgcn_mfma_f32_16x16x32_bf16(x0, wfrag[c + 0], ac0, 0, 0, 0);
                ac1 = __builtin_amdgcn_mfma_f32_16x16x32_bf16(x1, wfrag[c + 1], ac1, 0, 0, 0);
                ac2 = __builtin_amdgcn_mfma_f32_16x16x32_bf16(x2, wfrag[c + 2], ac2, 0, 0, 0);
                ac3 = __builtin_amdgcn_mfma_f32_16x16x32_bf16(x3, wfrag[c + 3], ac3, 0, 0, 0);
            }
            acc = (ac0 + ac1) + (ac2 + ac3);
        }
        // scatter z to LDS (C/D: col=lane&15, row=(lane>>4)*4+reg)
        {
            const int q4 = (lane >> 4) * 4;
            const int cl = f * 16 + (lane & 15);
            #pragma unroll
            for (int rg = 0; rg < 4; rg++) {
                ZL(g, q4 + rg, cl) = acc[rg];
            }
        }
        __syncthreads();       // S2: zl complete (and hsm reads drained)
        // gate math on threads 0..255 (wave-uniform branch)
        if (tid < 256) {
            float zi0 = ZL(0, grow, d0)     + bf2f_lo(zi_u);
            float zi1 = ZL(0, grow, d0 + 1) + bf2f_hi(zi_u);
            float zf0 = ZL(1, grow, d0)     + bf2f_lo(zf_u);
            float zf1 = ZL(1, grow, d0 + 1) + bf2f_hi(zf_u);
            float zg0 = ZL(2, grow, d0)     + bf2f_lo(zg_u);
            float zg1 = ZL(2, grow, d0 + 1) + bf2f_hi(zg_u);
            float zo0 = ZL(3, grow, d0)     + bf2f_lo(zo_u);
            float zo1 = ZL(3, grow, d0 + 1) + bf2f_hi(zo_u);

            ca = fast_sigmoid(zf0) * ca + fast_sigmoid(zi0) * fast_tanh(zg0);
            cb = fast_sigmoid(zf1) * cb + fast_sigmoid(zi1) * fast_tanh(zg1);
            float h0 = fast_sigmoid(zo0) * fast_tanh(ca);
            float h1 = fast_sigmoid(zo1) * fast_tanh(cb);

            unsigned hp = (unsigned)f2bf(h0) | ((unsigned)f2bf(h1) << 16);
            // publish: history and exchange in one store (write-through)
            __hip_atomic_store(Hsu + ((long)b_own * T_ + t) * 256 + nb * 16 + (tid & 15),
                               hp, __ATOMIC_RELAXED, __HIP_MEMORY_SCOPE_AGENT);
        }
        // no trailing sync: S1 of the next iteration protects zl reuse
    }
}

// ---------------------------------------------------------------------------
// Aspect normalization (unchanged)
// ---------------------------------------------------------------------------
__global__ __launch_bounds__(64)
void aspect_norm(const int* __restrict__ s,
                 const float* __restrict__ embed,
                 float* __restrict__ s_norm)
{
    __shared__ int sidx[256];
    const int tid = threadIdx.x;
    const int d = blockIdx.x * 64 + tid;
    for (int i = tid; i < 256; i += 64) sidx[i] = s[i];
    __syncthreads();
    float sum = 0.f, sq = 0.f;
    for (int i = 0; i < 256; i++) {
        float v = embed[(long)sidx[i] * D_ + d];
        sum += v; sq += v * v;
    }
    float mu = sum * (1.f / 256.f);
    float var = sq * (1.f / 256.f) - mu * mu;
    float rstd = rsqrtf(var + 1e-5f);
    for (int b = 0; b < 64; b++) {
        float acc = 0.f;
        #pragma unroll
        for (int a = 0; a < 4; a++) {
            acc += embed[(long)sidx[b * 4 + a] * D_ + d] - mu;
        }
        s_norm[b * D_ + d] = acc * rstd;
    }
}

// ---------------------------------------------------------------------------
// Softmax over T + r reduction (fast exp)
// ---------------------------------------------------------------------------
__global__ __launch_bounds__(256)
void attn_r(const float* __restrict__ apre,
            const unsigned short* __restrict__ Hs,
            float* __restrict__ r)
{
    const int b = blockIdx.y;
    const int d = blockIdx.x * 256 + threadIdx.x;
    const float* ap = apre + (long)b * T_ * D_ + d;
    const unsigned short* hp = Hs + (long)b * T_ * D_ + d;
    float mx = ap[0], sm = 1.f;
    for (int t = 1; t < T_; t++) {
        float v = ap[(long)t * D_];
        if (v > mx) { sm = sm * __expf(mx - v) + 1.f; mx = v; }
        else sm += __expf(v - mx);
    }
    float acc = 0.f;
    for (int t = 0; t < T_; t++) {
        acc += __expf(ap[(long)t * D_] - mx) * bf2f(hp[(long)t * D_]);
    }
    r[b * D_ + d] = acc / sm;
}

// ---------------------------------------------------------------------------
// h_star = tanh(r @ w_p^T + Hs[:, -1] @ w_x^T)
// ---------------------------------------------------------------------------
__global__ __launch_bounds__(256)
void hstar_kernel(const float* __restrict__ r,
                  const unsigned short* __restrict__ Hs,
                  const float* __restrict__ w_p,
                  const float* __restrict__ w_x,
                  float* __restrict__ h_star)
{
    __shared__ float rs[512];
    __shared__ float hts[512];
    const int b = blockIdx.x, tid = threadIdx.x;
    const long hlast = ((long)b * T_ + (T_ - 1)) * D_;
    rs[tid] = r[b * D_ + tid];
    rs[tid + 256] = r[b * D_ + 256 + tid];
    hts[tid] = bf2f(Hs[hlast + tid]);
    hts[tid + 256] = bf2f(Hs[hlast + 256 + tid]);
    __syncthreads();
    for (int d = tid; d < 512; d += 256) {
        const float* wp = w_p + (long)d * D_;
        const float* wx = w_x + (long)d * D_;
        float acc = 0.f;
        for (int e = 0; e < 512; e += 4) {
            float4 p1 = *(const float4*)(wp + e);
            float4 p2 = *(const float4*)(wx + e);
            acc += p1.x * rs[e] + p1.y * rs[e + 1] + p1.z * rs[e + 2] + p1.w * rs[e + 3];
            acc += p2.x * hts[e] + p2.y * hts[e + 1] + p2.z * hts[e + 2] + p2.w * hts[e + 3];
        }
        h_star[b * D_ + d] = fast_tanh(acc);
    }
}

// ---------------------------------------------------------------------------
// out = softmax(h_star @ w_f^T + b_f)
// ---------------------------------------------------------------------------
__global__ __launch_bounds__(256)
void out_kernel(const float* __restrict__ h_star,
                const float* __restrict__ w_f,
                const float* __restrict__ b_f,
                float* __restrict__ out)
{
    __shared__ float hs[512];
    __shared__ float lg[512];
    __shared__ float red[8];
    const int b = blockIdx.x, tid = threadIdx.x;
    hs[tid] = h_star[b * D_ + tid];
    hs[tid + 256] = h_star[b * D_ + 256 + tid];
    __syncthreads();
    for (int d = tid; d < 512; d += 256) {
        const float* wr = w_f + (long)d * D_;
        float acc = b_f[d];
        for (int e = 0; e < 512; e += 4) {
            float4 p = *(const float4*)(wr + e);
            acc += p.x * hs[e] + p.y * hs[e + 1] + p.z * hs[e + 2] + p.w * hs[e + 3];
        }
        lg[d] = acc;
    }
    __syncthreads();
    float m0 = fmaxf(lg[tid], lg[tid + 256]);
    for (int off = 32; off > 0; off >>= 1) m0 = fmaxf(m0, __shfl_down(m0, off, 64));
    if ((tid & 63) == 0) red[tid >> 6] = m0;
    __syncthreads();
    float bmax = fmaxf(fmaxf(red[0], red[1]), fmaxf(red[2], red[3]));
    float e0 = __expf(lg[tid] - bmax);
    float e1 = __expf(lg[tid + 256] - bmax);
    float s0 = e0 + e1;
    for (int off = 32; off > 0; off >>= 1) s0 += __shfl_down(s0, off, 64);
    if ((tid & 63) == 0) red[4 + (tid >> 6)] = s0;
    __syncthreads();
    float inv = 1.f / (red[4] + red[5] + red[6] + red[7]);
    out[b * D_ + tid] = e0 * inv;
    out[b * D_ + 256 + tid] = e1 * inv;
}

// ---------------------------------------------------------------------------
extern "C" void kernel_launch(void* const* d_in, const int* in_sizes, int n_in,
                              void* d_out, int out_size, void* d_ws, size_t ws_size,
                              hipStream_t stream)
{
    (void)in_sizes; (void)n_in; (void)out_size; (void)ws_size;

    const int* x = (const int*)d_in[0];
    const int* s = (const int*)d_in[1];
    const float* embed  = (const float*)d_in[2];
    const float* W_ih   = (const float*)d_in[3];
    const float* W_hh   = (const float*)d_in[4];
    const float* b_lstm = (const float*)d_in[5];
    const float* w_y = (const float*)d_in[6];
    const float* w_t = (const float*)d_in[7];
    const float* w_p = (const float*)d_in[8];
    const float* w_x = (const float*)d_in[9];
    const float* w_f = (const float*)d_in[10];
    const float* b_f = (const float*)d_in[11];

    // Workspace (overlaid), peak ~86.5 MB:
    //   [0,64MiB)   phase1: Zx bf16 [16384][2048]
    //               phase2: apre f32 @0, mbuf bf16 @32MiB, Ybuf bf16 @48MiB
    //   [64MiB,+16MiB) Hs bf16 (doubles as the h exchange; sentinel-filled)
    //   @86114304: s_norm, @86245376: rbuf, @86376448: hstar
    char* ws = (char*)d_ws;
    unsigned short* Zx   = (unsigned short*)(ws + 0);
    float*          apre = (float*)(ws + 0);
    unsigned short* mbuf = (unsigned short*)(ws + 33554432);
    unsigned short* Ybuf = (unsigned short*)(ws + 50331648);
    unsigned short* Hs   = (unsigned short*)(ws + 67108864);
    float* s_norm = (float*)(ws + 86114304);
    float* rbuf   = (float*)(ws + 86245376);
    float* hstar  = (float*)(ws + 86376448);

    // 0) sentinel-fill Hs (0xFF bytes -> 0xFFFFFFFF dwords = bf16 NaN pairs)
    hipMemsetAsync(Hs, 0xFF, (size_t)B_ * T_ * D_ * 2, stream);

    // 1) aspect normalization
    aspect_norm<<<dim3(8), dim3(64), 0, stream>>>(s, embed, s_norm);

    // 2) G1: Zx = embed[x] @ W_ih^T + b_lstm  (M=16384, N=2048, K=512)
    gemm_bt<<<dim3(16, 128, 1), dim3(256), 0, stream>>>(
        embed, 1, x, W_ih, nullptr, b_lstm, Zx, nullptr,
        2048, 512, 0L, 0L, 0);

    // 3) recurrence: ONE persistent kernel, 64 blocks x 512 threads
    persistent_lstm<<<dim3(64), dim3(512), 0, stream>>>(
        W_hh, Zx, (unsigned int*)Hs);

    // ---- phase 2: Zx dead; region reused for apre/mbuf/Ybuf ----

    // 4) G2: m[b] = Hs[b] @ circ(s_norm[b])^T  (M=256, N=512, K=512, 64 batches)
    gemm_bt<<<dim3(4, 2, 64), dim3(256), 0, stream>>>(
        Hs, 0, nullptr, nullptr, s_norm, nullptr, mbuf, nullptr,
        512, 512, (long)(T_ * D_), (long)(T_ * D_), 0);

    // 5) G3: Y = tanh(m @ w_y^T)  (M=16384, N=512, K=512)
    gemm_bt<<<dim3(4, 128, 1), dim3(256), 0, stream>>>(
        mbuf, 0, nullptr, w_y, nullptr, nullptr, Ybuf, nullptr,
        512, 512, 0L, 0L, 1);

    // 6) G4: apre = Y @ w_t^T
    gemm_bt<<<dim3(4, 128, 1), dim3(256), 0, stream>>>(
        Ybuf, 0, nullptr, w_t, nullptr, nullptr, nullptr, apre,
        512, 512, 0L, 0L, 0);

    // 7) softmax over T + r reduction
    attn_r<<<dim3(2, 64), dim3(256), 0, stream>>>(apre, Hs, rbuf);

    // 8) h_star
    hstar_kernel<<<dim3(64), dim3(256), 0, stream>>>(rbuf, Hs, w_p, w_x, hstar);

    // 9) final logits + softmax
    out_kernel<<<dim3(64), dim3(256), 0, stream>>>(hstar, w_f, b_f, (float*)d_out);
}

// Round 4
// 1043.114 us; speedup vs baseline: 1.3275x; 1.0495x over previous
//
#include <hip/hip_runtime.h>

// AF-LSTM on MI355X. Sizes fixed: V=32000, D=H=512, B=64, T=256, A=4, 4H=2048.
// All float tensors f32; x,s int32; d_out f32 [64,512].
// R11 (passed, 1095us): same-round poll check + 128x128 GEMM tile;
// persistent_lstm 543us (2.12us/step ~= 5090cy). MFMA busy ~126cy, VALU
// ~205cy per step -> ~4760cy is exchange wait (cross-XCD store visibility +
// poll RT + clique straggler skew).
// R12: XCD-local cliques. Blocks dispatch round-robin over 8 XCDs
// (bid%8 = XCD). Re-partition the recurrence into 8 cliques of 8 blocks,
// clique = bid&7 -> all members of a clique share one XCD, so the
// write-through store lands in the SAME L2 the consumers poll (~200-300cy RT
// instead of ~2000 cross-fabric). Each clique owns 8 batches; each member
// owns 64 h-cols (256 W_hh rows in regs, wfrag[2][16] = 128 VGPR,
// __launch_bounds__(512,2)). MFMA M=16 with 8 zero pad rows (zeroed once).
// Poll = 4 dwords/thread via the R8-proven ownership formula (dword width).
// Protocol semantics UNCHANGED (relaxed-agent dword loads/stores, sentinel
// 0xFFFFFFFF = bf16 NaN pair unreachable for sigmoid*tanh outputs), so
// correctness does not depend on the placement assumption.

typedef __bf16 bf16x8 __attribute__((ext_vector_type(8)));
typedef float f32x4 __attribute__((ext_vector_type(4)));

#define B_ 64
#define T_ 256
#define D_ 512
#define H4 2048

__device__ __forceinline__ unsigned short f2bf(float f) {
    unsigned u = __float_as_uint(f);
    u += 0x7fffu + ((u >> 16) & 1u);   // round-to-nearest-even
    return (unsigned short)(u >> 16);
}
__device__ __forceinline__ float bf2f(unsigned short x) {
    return __uint_as_float(((unsigned)x) << 16);
}
__device__ __forceinline__ float bf2f_lo(unsigned u) { return __uint_as_float(u << 16); }
__device__ __forceinline__ float bf2f_hi(unsigned u) { return __uint_as_float(u & 0xffff0000u); }

// fast transcendentals: v_exp_f32 and v_rcp_f32 (~1-2 ulp). h goes through
// bf16 (0.4% rel) every step anyway, so this is noise. Outputs stay in
// [0,1]/[-1,1] for all finite inputs, so the 0xFFFF sentinel is unreachable.
__device__ __forceinline__ float frcp(float x) { return __builtin_amdgcn_rcpf(x); }
__device__ __forceinline__ float fast_sigmoid(float x) {
    return frcp(1.f + __expf(-x));
}
__device__ __forceinline__ float fast_tanh(float x) {
    // tanh(x) = 1 - 2/(exp(2x)+1); saturates correctly at +/-inf
    return 1.f - 2.f * frcp(1.f + __expf(2.f * x));
}

// ---------------------------------------------------------------------------
// C = A @ B^T GEMM, bf16 MFMA 16x16x32. 128x128 block tile, 4 waves, each
// wave a 64x64 sub-tile as 4x4 fragments (16 MFMA / K-step). (unchanged R11)
// ---------------------------------------------------------------------------
__global__ __launch_bounds__(256)
void gemm_bt(const void* __restrict__ Abase, int a_f32,
             const int* __restrict__ gather_idx,
             const float* __restrict__ Bmat,
             const float* __restrict__ circ_src,
             const float* __restrict__ bias,
             unsigned short* __restrict__ outb,
             float* __restrict__ outf,
             int N, int K,
             long A_bstride, long out_bstride,
             int act)
{
    __shared__ __align__(16) unsigned short Asm[128 * 40];
    __shared__ __align__(16) unsigned short Bsm[128 * 40];

    const int bz = blockIdx.z;
    const int tile_n = blockIdx.x * 128;
    const int tile_m = blockIdx.y * 128;
    const int tid = threadIdx.x;
    const int lane = tid & 63;
    const int w = tid >> 6;
    const int wm = (w >> 1) * 64;
    const int wn = (w & 1) * 64;

    const int srow = tid >> 1;        // 0..127
    const int skc = (tid & 1) * 16;   // 0 or 16

    const float* arow_f = nullptr;
    const unsigned short* arow_h = nullptr;
    if (a_f32) {
        const float* Af = (const float*)Abase;
        if (gather_idx) arow_f = Af + (long)gather_idx[tile_m + srow] * K;
        else            arow_f = Af + (long)bz * A_bstride + (long)(tile_m + srow) * K;
    } else {
        arow_h = (const unsigned short*)Abase + (long)bz * A_bstride + (long)(tile_m + srow) * K;
    }
    const float* brow = nullptr;
    const float* csrc = nullptr;
    if (circ_src) csrc = circ_src + bz * 512;
    else brow = Bmat + (long)(tile_n + srow) * K;

    f32x4 zero4 = {0.f, 0.f, 0.f, 0.f};
    f32x4 acc[4][4];
    #pragma unroll
    for (int mi = 0; mi < 4; mi++)
        #pragma unroll
        for (int ni = 0; ni < 4; ni++) acc[mi][ni] = zero4;

    const int fr = lane & 15;
    const int fq = (lane >> 4) * 8;

    for (int kc = 0; kc < K; kc += 32) {
        __syncthreads();
        if (a_f32) {
            float4 u0 = *(const float4*)(arow_f + kc + skc);
            float4 u1 = *(const float4*)(arow_f + kc + skc + 4);
            float4 u2 = *(const float4*)(arow_f + kc + skc + 8);
            float4 u3 = *(const float4*)(arow_f + kc + skc + 12);
            unsigned short tmp[16] __attribute__((aligned(16)));
            tmp[0] = f2bf(u0.x); tmp[1] = f2bf(u0.y); tmp[2]  = f2bf(u0.z); tmp[3]  = f2bf(u0.w);
            tmp[4] = f2bf(u1.x); tmp[5] = f2bf(u1.y); tmp[6]  = f2bf(u1.z); tmp[7]  = f2bf(u1.w);
            tmp[8] = f2bf(u2.x); tmp[9] = f2bf(u2.y); tmp[10] = f2bf(u2.z); tmp[11] = f2bf(u2.w);
            tmp[12] = f2bf(u3.x); tmp[13] = f2bf(u3.y); tmp[14] = f2bf(u3.z); tmp[15] = f2bf(u3.w);
            *(uint4*)&Asm[srow * 40 + skc]     = *(const uint4*)tmp;
            *(uint4*)&Asm[srow * 40 + skc + 8] = *(const uint4*)(tmp + 8);
        } else {
            *(uint4*)&Asm[srow * 40 + skc]     = *(const uint4*)(arow_h + kc + skc);
            *(uint4*)&Asm[srow * 40 + skc + 8] = *(const uint4*)(arow_h + kc + skc + 8);
        }
        if (csrc) {
            unsigned short tmp[16] __attribute__((aligned(16)));
            int n_abs = tile_n + srow;
            #pragma unroll
            for (int j = 0; j < 16; j++) {
                int k_abs = kc + skc + j;
                tmp[j] = f2bf(csrc[(k_abs - n_abs) & 511]);
            }
            *(uint4*)&Bsm[srow * 40 + skc]     = *(const uint4*)tmp;
            *(uint4*)&Bsm[srow * 40 + skc + 8] = *(const uint4*)(tmp + 8);
        } else {
            float4 u0 = *(const float4*)(brow + kc + skc);
            float4 u1 = *(const float4*)(brow + kc + skc + 4);
            float4 u2 = *(const float4*)(brow + kc + skc + 8);
            float4 u3 = *(const float4*)(brow + kc + skc + 12);
            unsigned short tmp[16] __attribute__((aligned(16)));
            tmp[0] = f2bf(u0.x); tmp[1] = f2bf(u0.y); tmp[2]  = f2bf(u0.z); tmp[3]  = f2bf(u0.w);
            tmp[4] = f2bf(u1.x); tmp[5] = f2bf(u1.y); tmp[6]  = f2bf(u1.z); tmp[7]  = f2bf(u1.w);
            tmp[8] = f2bf(u2.x); tmp[9] = f2bf(u2.y); tmp[10] = f2bf(u2.z); tmp[11] = f2bf(u2.w);
            tmp[12] = f2bf(u3.x); tmp[13] = f2bf(u3.y); tmp[14] = f2bf(u3.z); tmp[15] = f2bf(u3.w);
            *(uint4*)&Bsm[srow * 40 + skc]     = *(const uint4*)tmp;
            *(uint4*)&Bsm[srow * 40 + skc + 8] = *(const uint4*)(tmp + 8);
        }
        __syncthreads();
        bf16x8 av[4], bv[4];
        #pragma unroll
        for (int mi = 0; mi < 4; mi++)
            av[mi] = *(const bf16x8*)&Asm[(wm + mi * 16 + fr) * 40 + fq];
        #pragma unroll
        for (int ni = 0; ni < 4; ni++)
            bv[ni] = *(const bf16x8*)&Bsm[(wn + ni * 16 + fr) * 40 + fq];
        #pragma unroll
        for (int mi = 0; mi < 4; mi++)
            #pragma unroll
            for (int ni = 0; ni < 4; ni++)
                acc[mi][ni] = __builtin_amdgcn_mfma_f32_16x16x32_bf16(
                    av[mi], bv[ni], acc[mi][ni], 0, 0, 0);
    }

    #pragma unroll
    for (int mi = 0; mi < 4; mi++) {
        #pragma unroll
        for (int ni = 0; ni < 4; ni++) {
            #pragma unroll
            for (int rg = 0; rg < 4; rg++) {
                int row = tile_m + wm + mi * 16 + (lane >> 4) * 4 + rg;
                int col = tile_n + wn + ni * 16 + (lane & 15);
                float v = acc[mi][ni][rg];
                if (bias) v += bias[col];
                if (act == 1) v = fast_tanh(v);
                long oidx = (long)bz * out_bstride + (long)row * N + col;
                if (outb) outb[oidx] = f2bf(v);
                else outf[oidx] = v;
            }
        }
    }
}

// ---------------------------------------------------------------------------
// Persistent LSTM recurrence, 64 blocks x 512 threads (8 waves).
// R12 partition: clique cq = bid&7 (-> one XCD under round-robin dispatch),
// member nbp = bid>>3 (0..7). Clique owns batches [cq*8,+8); member owns
// h-cols [nbp*64,+64) => 256 W_hh rows in registers (wfrag[2][16]/lane).
// Per step: poll 2048 dwords of Hs[cq*8..+8][t-1][*] (4 dwords/thread),
// stage to hsm rows 0..7 (rows 8..15 zero pad for MFMA M=16), 32 MFMAs/wave
// (2 N-frags x 16 k, 4 indep chains each), zl scatter, gate math on threads
// 0..255 (8 batches x 32 col-pairs), publish 256 dwords.
// Sync: NO flags, NO fences; sentinel-filled Hs; relaxed-agent dword ops.
// ---------------------------------------------------------------------------
#define WSTRIDE 520
#define SENT 0xFFFFFFFFu
#define ZL(g,r,d) zl[((g)*8+(r))*65+(d)]

__global__ __launch_bounds__(512, 2)
void persistent_lstm(const float* __restrict__ Whh,         // f32 [2048][512]
                     const unsigned short* __restrict__ Zx, // bf16 [16384][2048]
                     unsigned int* __restrict__ Hsu)        // Hs as dwords [64*256*256]
{
    __shared__ __align__(16) unsigned short hsm[16 * WSTRIDE];  // 16,640 B
    __shared__ float zl[4 * 8 * 65];                            //  8,320 B

    const int cq  = blockIdx.x & 7;   // clique id (== XCD under RR dispatch)
    const int nbp = blockIdx.x >> 3;  // column-owner within clique, 0..7
    const int tid = threadIdx.x;
    const int w = tid >> 6;        // 0..7
    const int lane = tid & 63;
    const int fr = lane & 15;
    const int fq = (lane >> 4) * 8;
    const int g = w >> 1;          // gate 0..3 (i,f,g,o)
    const int f = w & 1;           // 32-col half within member's 64 cols

    // ---- one-time: this wave's 32 W_hh rows into registers (2 frags) ----
    bf16x8 wfrag[2][16];
    #pragma unroll
    for (int n = 0; n < 2; n++) {
        const float* wrow = Whh + (long)(g * 512 + nbp * 64 + f * 32 + n * 16 + fr) * 512;
        #pragma unroll
        for (int c = 0; c < 16; c++) {
            int k0 = c * 32 + fq;
            float4 u0 = *(const float4*)(wrow + k0);
            float4 u1 = *(const float4*)(wrow + k0 + 4);
            unsigned short tmp[8] __attribute__((aligned(16)));
            tmp[0] = f2bf(u0.x); tmp[1] = f2bf(u0.y); tmp[2] = f2bf(u0.z); tmp[3] = f2bf(u0.w);
            tmp[4] = f2bf(u1.x); tmp[5] = f2bf(u1.y); tmp[6] = f2bf(u1.z); tmp[7] = f2bf(u1.w);
            wfrag[n][c] = *(const bf16x8*)tmp;
        }
    }

    // zero hsm once (rows 8..15 stay zero = MFMA pad rows). Visible to all
    // threads after the first barrier (S2 of t=0) before any hsm read (t=1).
    for (int i = tid; i < 16 * WSTRIDE / 2; i += 512)
        ((unsigned*)hsm)[i] = 0;

    // poll/staging ownership (R8-formula, 4 dwords): idx = k*512+tid,
    // row pr = idx>>8 (0..7), dword dp = idx&255
    int st_r[4], st_dp[4];
    #pragma unroll
    for (int k = 0; k < 4; k++) {
        int idx = k * 512 + tid;
        st_r[k] = idx >> 8;
        st_dp[k] = idx & 255;
    }

    // gate-math ownership (threads 0..255): batch grow 0..7, col pair d0
    const int grow = (tid & 255) >> 5;
    const int d0 = (tid & 31) * 2;
    const int b_own = cq * 8 + grow;
    const int dg = nbp * 64 + d0;
    float ca = 0.f, cb = 0.f;      // cell state in registers (threads < 256)

    f32x4 zero4 = {0.f, 0.f, 0.f, 0.f};

    for (int t = 0; t < T_; t++) {
        // Zx gate pre-activations: independent of h -> issue early
        unsigned zi_u = 0, zf_u = 0, zg_u = 0, zo_u = 0;
        if (tid < 256) {
            const long zb = ((long)b_own * T_ + t) * H4 + dg;
            zi_u = *(const unsigned*)&Zx[zb + 0 * 512];
            zf_u = *(const unsigned*)&Zx[zb + 1 * 512];
            zg_u = *(const unsigned*)&Zx[zb + 2 * 512];
            zo_u = *(const unsigned*)&Zx[zb + 3 * 512];
        }

        f32x4 an0 = zero4, an1 = zero4;
        if (t > 0) {
            // poll-stage h_{t-1}: 2048 dwords of Hs[cq*8..+8][t-1][*]
            unsigned vv[4];
            long ad[4];
            #pragma unroll
            for (int k = 0; k < 4; k++) {
                ad[k] = ((long)(cq * 8 + st_r[k]) * T_ + (t - 1)) * 256 + st_dp[k];
                vv[k] = __hip_atomic_load(Hsu + ad[k], __ATOMIC_RELAXED,
                                          __HIP_MEMORY_SCOPE_AGENT);
            }
            // check current values; if any pending, reload ALL (grouped) and
            // re-check the freshly loaded values in the same round.
            while (true) {
                bool pend = false;
                #pragma unroll
                for (int k = 0; k < 4; k++) pend |= (vv[k] == SENT);
                if (!__ballot(pend)) break;
                #pragma unroll
                for (int k = 0; k < 4; k++) {
                    vv[k] = __hip_atomic_load(Hsu + ad[k], __ATOMIC_RELAXED,
                                              __HIP_MEMORY_SCOPE_AGENT);
                }
            }
            #pragma unroll
            for (int k = 0; k < 4; k++) {
                *(unsigned*)&hsm[st_r[k] * WSTRIDE + st_dp[k] * 2] = vv[k];
            }
            __syncthreads();   // S1: hsm staged (also fences prev-iter zl reads)
            // z_frags = h_{t-1}[16x512 padded] @ Wfrags^T : 2 x 16 MFMAs,
            // 4 independent accumulator chains per frag, shared A loads
            const unsigned short* arow = hsm + fr * WSTRIDE;
            f32x4 a0[4] = {zero4, zero4, zero4, zero4};
            f32x4 a1[4] = {zero4, zero4, zero4, zero4};
            #pragma unroll
            for (int c = 0; c < 16; c += 4) {
                bf16x8 x0 = *(const bf16x8*)(arow + (c + 0) * 32 + fq);
                bf16x8 x1 = *(const bf16x8*)(arow + (c + 1) * 32 + fq);
                bf16x8 x2 = *(const bf16x8*)(arow + (c + 2) * 32 + fq);
                bf16x8 x3 = *(const bf16x8*)(arow + (c + 3) * 32 + fq);
                a0[0] = __builtin_amdgcn_mfma_f32_16x16x32_bf16(x0, wfrag[0][c + 0], a0[0], 0, 0, 0);
                a0[1] = __builtin_amdgcn_mfma_f32_16x16x32_bf16(x1, wfrag[0][c + 1], a0[1], 0, 0, 0);
                a0[2] = __builtin_amdgcn_mfma_f32_16x16x32_bf16(x2, wfrag[0][c + 2], a0[2], 0, 0, 0);
                a0[3] = __builtin_amdgcn_mfma_f32_16x16x32_bf16(x3, wfrag[0][c + 3], a0[3], 0, 0, 0);
                a1[0] = __builtin_amdgcn_mfma_f32_16x16x32_bf16(x0, wfrag[1][c + 0], a1[0], 0, 0, 0);
                a1[1] = __builtin_amdgcn_mfma_f32_16x16x32_bf16(x1, wfrag[1][c + 1], a1[1], 0, 0, 0);
                a1[2] = __builtin_amdgcn_mfma_f32_16x16x32_bf16(x2, wfrag[1][c + 2], a1[2], 0, 0, 0);
                a1[3] = __builtin_amdgcn_mfma_f32_16x16x32_bf16(x3, wfrag[1][c + 3], a1[3], 0, 0, 0);
            }
            an0 = (a0[0] + a0[1]) + (a0[2] + a0[3]);
            an1 = (a1[0] + a1[1]) + (a1[2] + a1[3]);
        }
        // scatter z to LDS (C/D: col=lane&15, row=(lane>>4)*4+reg);
        // only batch rows 0..7 are real -> lanes 0..31
        if (lane < 32) {
            const int rb = (lane >> 4) * 4;           // 0 or 4
            const int cl = f * 32 + (lane & 15);
            #pragma unroll
            for (int rg = 0; rg < 4; rg++) {
                ZL(g, rb + rg, cl)      = an0[rg];
                ZL(g, rb + rg, cl + 16) = an1[rg];
            }
        }
        __syncthreads();       // S2: zl complete (and hsm reads drained)
        // gate math on threads 0..255 (wave-uniform branch)
        if (tid < 256) {
            float zi0 = ZL(0, grow, d0)     + bf2f_lo(zi_u);
            float zi1 = ZL(0, grow, d0 + 1) + bf2f_hi(zi_u);
            float zf0 = ZL(1, grow, d0)     + bf2f_lo(zf_u);
            float zf1 = ZL(1, grow, d0 + 1) + bf2f_hi(zf_u);
            float zg0 = ZL(2, grow, d0)     + bf2f_lo(zg_u);
            float zg1 = ZL(2, grow, d0 + 1) + bf2f_hi(zg_u);
            float zo0 = ZL(3, grow, d0)     + bf2f_lo(zo_u);
            float zo1 = ZL(3, grow, d0 + 1) + bf2f_hi(zo_u);

            ca = fast_sigmoid(zf0) * ca + fast_sigmoid(zi0) * fast_tanh(zg0);
            cb = fast_sigmoid(zf1) * cb + fast_sigmoid(zi1) * fast_tanh(zg1);
            float h0 = fast_sigmoid(zo0) * fast_tanh(ca);
            float h1 = fast_sigmoid(zo1) * fast_tanh(cb);

            unsigned hp = (unsigned)f2bf(h0) | ((unsigned)f2bf(h1) << 16);
            // publish: history and exchange in one store (write-through)
            __hip_atomic_store(Hsu + ((long)b_own * T_ + t) * 256 + nbp * 32 + (tid & 31),
                               hp, __ATOMIC_RELAXED, __HIP_MEMORY_SCOPE_AGENT);
        }
        // no trailing sync: S1 of the next iteration protects zl reuse
    }
}

// ---------------------------------------------------------------------------
// Aspect normalization (unchanged)
// ---------------------------------------------------------------------------
__global__ __launch_bounds__(64)
void aspect_norm(const int* __restrict__ s,
                 const float* __restrict__ embed,
                 float* __restrict__ s_norm)
{
    __shared__ int sidx[256];
    const int tid = threadIdx.x;
    const int d = blockIdx.x * 64 + tid;
    for (int i = tid; i < 256; i += 64) sidx[i] = s[i];
    __syncthreads();
    float sum = 0.f, sq = 0.f;
    for (int i = 0; i < 256; i++) {
        float v = embed[(long)sidx[i] * D_ + d];
        sum += v; sq += v * v;
    }
    float mu = sum * (1.f / 256.f);
    float var = sq * (1.f / 256.f) - mu * mu;
    float rstd = rsqrtf(var + 1e-5f);
    for (int b = 0; b < 64; b++) {
        float acc = 0.f;
        #pragma unroll
        for (int a = 0; a < 4; a++) {
            acc += embed[(long)sidx[b * 4 + a] * D_ + d] - mu;
        }
        s_norm[b * D_ + d] = acc * rstd;
    }
}

// ---------------------------------------------------------------------------
// Softmax over T + r reduction (fast exp)
// ---------------------------------------------------------------------------
__global__ __launch_bounds__(256)
void attn_r(const float* __restrict__ apre,
            const unsigned short* __restrict__ Hs,
            float* __restrict__ r)
{
    const int b = blockIdx.y;
    const int d = blockIdx.x * 256 + threadIdx.x;
    const float* ap = apre + (long)b * T_ * D_ + d;
    const unsigned short* hp = Hs + (long)b * T_ * D_ + d;
    float mx = ap[0], sm = 1.f;
    for (int t = 1; t < T_; t++) {
        float v = ap[(long)t * D_];
        if (v > mx) { sm = sm * __expf(mx - v) + 1.f; mx = v; }
        else sm += __expf(v - mx);
    }
    float acc = 0.f;
    for (int t = 0; t < T_; t++) {
        acc += __expf(ap[(long)t * D_] - mx) * bf2f(hp[(long)t * D_]);
    }
    r[b * D_ + d] = acc / sm;
}

// ---------------------------------------------------------------------------
// h_star = tanh(r @ w_p^T + Hs[:, -1] @ w_x^T)
// ---------------------------------------------------------------------------
__global__ __launch_bounds__(256)
void hstar_kernel(const float* __restrict__ r,
                  const unsigned short* __restrict__ Hs,
                  const float* __restrict__ w_p,
                  const float* __restrict__ w_x,
                  float* __restrict__ h_star)
{
    __shared__ float rs[512];
    __shared__ float hts[512];
    const int b = blockIdx.x, tid = threadIdx.x;
    const long hlast = ((long)b * T_ + (T_ - 1)) * D_;
    rs[tid] = r[b * D_ + tid];
    rs[tid + 256] = r[b * D_ + 256 + tid];
    hts[tid] = bf2f(Hs[hlast + tid]);
    hts[tid + 256] = bf2f(Hs[hlast + 256 + tid]);
    __syncthreads();
    for (int d = tid; d < 512; d += 256) {
        const float* wp = w_p + (long)d * D_;
        const float* wx = w_x + (long)d * D_;
        float acc = 0.f;
        for (int e = 0; e < 512; e += 4) {
            float4 p1 = *(const float4*)(wp + e);
            float4 p2 = *(const float4*)(wx + e);
            acc += p1.x * rs[e] + p1.y * rs[e + 1] + p1.z * rs[e + 2] + p1.w * rs[e + 3];
            acc += p2.x * hts[e] + p2.y * hts[e + 1] + p2.z * hts[e + 2] + p2.w * hts[e + 3];
        }
        h_star[b * D_ + d] = fast_tanh(acc);
    }
}

// ---------------------------------------------------------------------------
// out = softmax(h_star @ w_f^T + b_f)
// ---------------------------------------------------------------------------
__global__ __launch_bounds__(256)
void out_kernel(const float* __restrict__ h_star,
                const float* __restrict__ w_f,
                const float* __restrict__ b_f,
                float* __restrict__ out)
{
    __shared__ float hs[512];
    __shared__ float lg[512];
    __shared__ float red[8];
    const int b = blockIdx.x, tid = threadIdx.x;
    hs[tid] = h_star[b * D_ + tid];
    hs[tid + 256] = h_star[b * D_ + 256 + tid];
    __syncthreads();
    for (int d = tid; d < 512; d += 256) {
        const float* wr = w_f + (long)d * D_;
        float acc = b_f[d];
        for (int e = 0; e < 512; e += 4) {
            float4 p = *(const float4*)(wr + e);
            acc += p.x * hs[e] + p.y * hs[e + 1] + p.z * hs[e + 2] + p.w * hs[e + 3];
        }
        lg[d] = acc;
    }
    __syncthreads();
    float m0 = fmaxf(lg[tid], lg[tid + 256]);
    for (int off = 32; off > 0; off >>= 1) m0 = fmaxf(m0, __shfl_down(m0, off, 64));
    if ((tid & 63) == 0) red[tid >> 6] = m0;
    __syncthreads();
    float bmax = fmaxf(fmaxf(red[0], red[1]), fmaxf(red[2], red[3]));
    float e0 = __expf(lg[tid] - bmax);
    float e1 = __expf(lg[tid + 256] - bmax);
    float s0 = e0 + e1;
    for (int off = 32; off > 0; off >>= 1) s0 += __shfl_down(s0, off, 64);
    if ((tid & 63) == 0) red[4 + (tid >> 6)] = s0;
    __syncthreads();
    float inv = 1.f / (red[4] + red[5] + red[6] + red[7]);
    out[b * D_ + tid] = e0 * inv;
    out[b * D_ + 256 + tid] = e1 * inv;
}

// ---------------------------------------------------------------------------
extern "C" void kernel_launch(void* const* d_in, const int* in_sizes, int n_in,
                              void* d_out, int out_size, void* d_ws, size_t ws_size,
                              hipStream_t stream)
{
    (void)in_sizes; (void)n_in; (void)out_size; (void)ws_size;

    const int* x = (const int*)d_in[0];
    const int* s = (const int*)d_in[1];
    const float* embed  = (const float*)d_in[2];
    const float* W_ih   = (const float*)d_in[3];
    const float* W_hh   = (const float*)d_in[4];
    const float* b_lstm = (const float*)d_in[5];
    const float* w_y = (const float*)d_in[6];
    const float* w_t = (const float*)d_in[7];
    const float* w_p = (const float*)d_in[8];
    const float* w_x = (const float*)d_in[9];
    const float* w_f = (const float*)d_in[10];
    const float* b_f = (const float*)d_in[11];

    // Workspace (overlaid), peak ~86.5 MB:
    //   [0,64MiB)   phase1: Zx bf16 [16384][2048]
    //               phase2: apre f32 @0, mbuf bf16 @32MiB, Ybuf bf16 @48MiB
    //   [64MiB,+16MiB) Hs bf16 (doubles as the h exchange; sentinel-filled)
    //   @86114304: s_norm, @86245376: rbuf, @86376448: hstar
    char* ws = (char*)d_ws;
    unsigned short* Zx   = (unsigned short*)(ws + 0);
    float*          apre = (float*)(ws + 0);
    unsigned short* mbuf = (unsigned short*)(ws + 33554432);
    unsigned short* Ybuf = (unsigned short*)(ws + 50331648);
    unsigned short* Hs   = (unsigned short*)(ws + 67108864);
    float* s_norm = (float*)(ws + 86114304);
    float* rbuf   = (float*)(ws + 86245376);
    float* hstar  = (float*)(ws + 86376448);

    // 0) sentinel-fill Hs (0xFF bytes -> 0xFFFFFFFF dwords = bf16 NaN pairs)
    hipMemsetAsync(Hs, 0xFF, (size_t)B_ * T_ * D_ * 2, stream);

    // 1) aspect normalization
    aspect_norm<<<dim3(8), dim3(64), 0, stream>>>(s, embed, s_norm);

    // 2) G1: Zx = embed[x] @ W_ih^T + b_lstm  (M=16384, N=2048, K=512)
    gemm_bt<<<dim3(16, 128, 1), dim3(256), 0, stream>>>(
        embed, 1, x, W_ih, nullptr, b_lstm, Zx, nullptr,
        2048, 512, 0L, 0L, 0);

    // 3) recurrence: ONE persistent kernel, 64 blocks x 512 threads
    persistent_lstm<<<dim3(64), dim3(512), 0, stream>>>(
        W_hh, Zx, (unsigned int*)Hs);

    // ---- phase 2: Zx dead; region reused for apre/mbuf/Ybuf ----

    // 4) G2: m[b] = Hs[b] @ circ(s_norm[b])^T  (M=256, N=512, K=512, 64 batches)
    gemm_bt<<<dim3(4, 2, 64), dim3(256), 0, stream>>>(
        Hs, 0, nullptr, nullptr, s_norm, nullptr, mbuf, nullptr,
        512, 512, (long)(T_ * D_), (long)(T_ * D_), 0);

    // 5) G3: Y = tanh(m @ w_y^T)  (M=16384, N=512, K=512)
    gemm_bt<<<dim3(4, 128, 1), dim3(256), 0, stream>>>(
        mbuf, 0, nullptr, w_y, nullptr, nullptr, Ybuf, nullptr,
        512, 512, 0L, 0L, 1);

    // 6) G4: apre = Y @ w_t^T
    gemm_bt<<<dim3(4, 128, 1), dim3(256), 0, stream>>>(
        Ybuf, 0, nullptr, w_t, nullptr, nullptr, nullptr, apre,
        512, 512, 0L, 0L, 0);

    // 7) softmax over T + r reduction
    attn_r<<<dim3(2, 64), dim3(256), 0, stream>>>(apre, Hs, rbuf);

    // 8) h_star
    hstar_kernel<<<dim3(64), dim3(256), 0, stream>>>(rbuf, Hs, w_p, w_x, hstar);

    // 9) final logits + softmax
    out_kernel<<<dim3(64), dim3(256), 0, stream>>>(hstar, w_f, b_f, (float*)d_out);
}